// Round 2
// baseline (824.755 us; speedup 1.0000x reference)
//
#include <hip/hip_runtime.h>
#include <hip/hip_bf16.h>

// ---------------------------------------------------------------------------
// MultiHeadAttention: B=4, T=1024, E=768, D=768, H=8, per-head full-width proj
// All GEMMs via bf16 MFMA (m97 128x128 structure). Attention chunked over
// (b,h) z-slices so workspace fits ws_size (CH heads/chunk, CH in {8,4,2,1}).
// ---------------------------------------------------------------------------

typedef __bf16 bf16x8 __attribute__((ext_vector_type(8)));
typedef float  f32x4  __attribute__((ext_vector_type(4)));
typedef short  s16x4  __attribute__((ext_vector_type(4)));

#define AS1 __attribute__((address_space(1)))
#define AS3 __attribute__((address_space(3)))

__device__ inline void gload_lds16(const void* g, void* l) {
  // async global->LDS, 16B per lane; LDS dest is wave-uniform base + lane*16
  __builtin_amdgcn_global_load_lds((AS1 const void*)g, (AS3 void*)l, 16, 0, 0);
}

__device__ inline unsigned short f2bf(float f) {  // RNE f32 -> bf16 bits
  union { float f; unsigned u; } c; c.f = f;
  unsigned r = c.u + 0x7FFF + ((c.u >> 16) & 1);
  return (unsigned short)(r >> 16);
}
__device__ inline float bf2f(unsigned short u) {
  return __uint_as_float(((unsigned)u) << 16);
}

// ---------------------------------------------------------------------------
// GEMM: C = scale * A * Bt^T (+ bias[z*biasZ + n]); A:[M,K] bf16, Bt:[N,K] bf16
//   zoff  = (z>>zShift)*cZhi + (z & ((1<<zShift)-1))*cZlo
//   rowoff= (m>>rowShift)*cRowHi + (m & ((1<<rowShift)-1))*ldc
//   C[zoff + rowoff + n]
// Grid: (N/128, M/128, Z). 256 threads = 4 waves, each wave 64x64 output.
// ---------------------------------------------------------------------------
template<bool OUT_F32>
__global__ __launch_bounds__(256, 2)
void gemm_bt_kernel(const unsigned short* __restrict__ A,
                    const unsigned short* __restrict__ Bt,
                    void* __restrict__ Cout,
                    const float* __restrict__ bias,
                    int K,
                    long long aZ, long long bZ,
                    long long cZhi, long long cZlo, int zShift,
                    long long cRowHi, int rowShift, int ldc,
                    long long biasZ, float scale)
{
  __shared__ unsigned short As[128 * 64];
  __shared__ unsigned short Bs[128 * 64];

  const int tid  = threadIdx.x;
  const int wave = tid >> 6;
  const int lane = tid & 63;
  const int wm = wave >> 1, wn = wave & 1;

  const int mtile = blockIdx.y, ntile = blockIdx.x;
  const int z = blockIdx.z;

  const unsigned short* Ab = A  + (size_t)z * aZ + (size_t)mtile * 128 * K;
  const unsigned short* Bb = Bt + (size_t)z * bZ + (size_t)ntile * 128 * K;

  // staging: each wave stages 32 rows of A and 32 rows of Bt (4 issues x 8 rows)
  const int rlane = lane >> 3;          // 0..7 row within 8-row group
  const int ck    = (lane & 7) * 8;     // bf16 column within 64-wide K tile

  f32x4 acc[4][4] = {};

  const int nkt = K >> 6;
  for (int kt = 0; kt < nkt; ++kt) {
    const int kbase = kt * 64;
    __syncthreads();  // previous iter's LDS reads done before overwrite
#pragma unroll
    for (int i = 0; i < 4; ++i) {
      const int r = wave * 32 + i * 8;          // wave-uniform base row
      gload_lds16(Ab + (size_t)(r + rlane) * K + kbase + ck, &As[r * 64]);
      gload_lds16(Bb + (size_t)(r + rlane) * K + kbase + ck, &Bs[r * 64]);
    }
    __syncthreads();  // drains vmcnt(0) before barrier -> tiles ready
#pragma unroll
    for (int kk = 0; kk < 2; ++kk) {
      const int koff = kk * 32 + (lane >> 4) * 8;
      bf16x8 af[4], bfr[4];
#pragma unroll
      for (int f = 0; f < 4; ++f) {
        af[f]  = *(const bf16x8*)&As[(wm * 64 + f * 16 + (lane & 15)) * 64 + koff];
        bfr[f] = *(const bf16x8*)&Bs[(wn * 64 + f * 16 + (lane & 15)) * 64 + koff];
      }
#pragma unroll
      for (int fm = 0; fm < 4; ++fm)
#pragma unroll
        for (int fn = 0; fn < 4; ++fn)
          acc[fm][fn] = __builtin_amdgcn_mfma_f32_16x16x32_bf16(af[fm], bfr[fn], acc[fm][fn], 0, 0, 0);
    }
  }

  // epilogue: C/D frag layout: col = lane&15, row = (lane>>4)*4 + j  [m89]
  const long long zoff = (long long)(z >> zShift) * cZhi
                       + (long long)(z & ((1 << zShift) - 1)) * cZlo;
#pragma unroll
  for (int fm = 0; fm < 4; ++fm) {
#pragma unroll
    for (int j = 0; j < 4; ++j) {
      const int m = mtile * 128 + wm * 64 + fm * 16 + (lane >> 4) * 4 + j;
      const long long rowoff = (long long)(m >> rowShift) * cRowHi
                             + (long long)(m & ((1 << rowShift) - 1)) * ldc;
#pragma unroll
      for (int fn = 0; fn < 4; ++fn) {
        const int n = ntile * 128 + wn * 64 + fn * 16 + (lane & 15);
        float v = acc[fm][fn][j] * scale;
        if (bias) v += bias[(size_t)z * biasZ + n];
        const long long cidx = zoff + rowoff + n;
        if (OUT_F32) ((float*)Cout)[cidx] = v;
        else ((unsigned short*)Cout)[cidx] = f2bf(v);
      }
    }
  }
}

// fp32 [Z][R][C] -> bf16 [Z][C][R] tile transpose+convert
__global__ void transpose_conv_kernel(const float* __restrict__ in,
                                      unsigned short* __restrict__ out,
                                      int R, int C)
{
  __shared__ float tile[32][33];
  const size_t zo = (size_t)blockIdx.z * R * C;
  const int c0 = blockIdx.x * 32, r0 = blockIdx.y * 32;
  const int tx = threadIdx.x, ty = threadIdx.y;
#pragma unroll
  for (int i = ty; i < 32; i += 8)
    tile[i][tx] = in[zo + (size_t)(r0 + i) * C + c0 + tx];
  __syncthreads();
#pragma unroll
  for (int i = ty; i < 32; i += 8)
    out[zo + (size_t)(c0 + i) * R + r0 + tx] = f2bf(tile[tx][i]);
}

// bf16 [Z][R][C] -> bf16 [Z][C][R]
__global__ void transpose_bf16_kernel(const unsigned short* __restrict__ in,
                                      unsigned short* __restrict__ out,
                                      int R, int C)
{
  __shared__ unsigned short tile[32][33];
  const size_t zo = (size_t)blockIdx.z * R * C;
  const int c0 = blockIdx.x * 32, r0 = blockIdx.y * 32;
  const int tx = threadIdx.x, ty = threadIdx.y;
#pragma unroll
  for (int i = ty; i < 32; i += 8)
    tile[i][tx] = in[zo + (size_t)(r0 + i) * C + c0 + tx];
  __syncthreads();
#pragma unroll
  for (int i = ty; i < 32; i += 8)
    out[zo + (size_t)(c0 + i) * R + r0 + tx] = tile[tx][i];
}

__global__ void convert_f32_bf16_kernel(const float* __restrict__ in,
                                        unsigned short* __restrict__ out, int n4)
{
  const int i = blockIdx.x * blockDim.x + threadIdx.x;
  if (i < n4) {
    const float4 f = ((const float4*)in)[i];
    s16x4 o;
    o[0] = (short)f2bf(f.x); o[1] = (short)f2bf(f.y);
    o[2] = (short)f2bf(f.z); o[3] = (short)f2bf(f.w);
    ((s16x4*)out)[i] = o;
  }
}

__global__ void bosum_kernel(const float* __restrict__ bo, float* __restrict__ bos)
{
  const int e = blockIdx.x * blockDim.x + threadIdx.x;
  if (e < 768) {
    float s = 0.f;
#pragma unroll
    for (int h = 0; h < 8; ++h) s += bo[h * 768 + e];
    bos[e] = s;
  }
}

// in-place row softmax on bf16 [rows][1024]; one block (256 thr) per row
__global__ __launch_bounds__(256)
void softmax_kernel(unsigned short* __restrict__ S)
{
  const size_t row = blockIdx.x;
  unsigned short* p = S + row * 1024;
  const int t = threadIdx.x;

  s16x4 raw = *((const s16x4*)p + t);
  float v[4];
#pragma unroll
  for (int j = 0; j < 4; ++j) v[j] = bf2f((unsigned short)raw[j]);

  float mx = fmaxf(fmaxf(v[0], v[1]), fmaxf(v[2], v[3]));
#pragma unroll
  for (int o = 1; o < 64; o <<= 1) mx = fmaxf(mx, __shfl_xor(mx, o));

  __shared__ float red[8];
  if ((t & 63) == 0) red[t >> 6] = mx;
  __syncthreads();
  mx = fmaxf(fmaxf(red[0], red[1]), fmaxf(red[2], red[3]));

  float e[4], s = 0.f;
#pragma unroll
  for (int j = 0; j < 4; ++j) { e[j] = __expf(v[j] - mx); s += e[j]; }
#pragma unroll
  for (int o = 1; o < 64; o <<= 1) s += __shfl_xor(s, o);
  if ((t & 63) == 0) red[4 + (t >> 6)] = s;
  __syncthreads();
  s = red[4] + red[5] + red[6] + red[7];
  const float inv = 1.0f / s;

  s16x4 outv;
#pragma unroll
  for (int j = 0; j < 4; ++j) outv[j] = (short)f2bf(e[j] * inv);
  *((s16x4*)p + t) = outv;
}

// ---------------------------------------------------------------------------
extern "C" void kernel_launch(void* const* d_in, const int* in_sizes, int n_in,
                              void* d_out, int out_size, void* d_ws, size_t ws_size,
                              hipStream_t stream)
{
  (void)in_sizes; (void)n_in; (void)out_size;
  constexpr int Bb = 4, T = 1024, E = 768, D = 768, H = 8;
  constexpr int HD = H * D;                          // 6144
  constexpr long long TD = (long long)T * D;         // 786432
  constexpr long long TT = (long long)T * T;         // 1048576
  constexpr long long DE = (long long)D * E;         // 589824
  constexpr long long DT = (long long)D * T;         // 786432

  const float* x  = (const float*)d_in[0];
  const float* wq = (const float*)d_in[1];
  const float* bq = (const float*)d_in[2];
  const float* wk = (const float*)d_in[3];
  const float* bk = (const float*)d_in[4];
  const float* wv = (const float*)d_in[5];
  const float* bv = (const float*)d_in[6];
  const float* wo = (const float*)d_in[7];
  const float* bo = (const float*)d_in[8];
  float* out = (float*)d_out;

  // ----- choose CH (heads per chunk) from ws_size; deterministic -----
  // fixed = xb + 3*wT + bos + z2 = 84,937,728 B; per-chunk = CH * 8,388,608 B
  const size_t FIXED = 84937728ULL;
  const size_t PERCH = 8388608ULL;
  int CH = 8;
  while (CH > 1 && FIXED + (size_t)CH * PERCH > ws_size) CH >>= 1;

  unsigned char* wsb = (unsigned char*)d_ws;
  size_t off = 0;
  auto carve = [&](size_t bytes) -> void* {
    void* p = wsb + off;
    off += (bytes + 255) & ~(size_t)255;
    return p;
  };
  unsigned short* xb  = (unsigned short*)carve((size_t)Bb * T * E * 2);  // [4096,768]
  unsigned short* wqT = (unsigned short*)carve((size_t)H * D * E * 2);   // [H,D,E]
  unsigned short* wkT = (unsigned short*)carve((size_t)H * D * E * 2);
  unsigned short* wvT = (unsigned short*)carve((size_t)H * D * E * 2);
  float*          bos = (float*)carve(E * 4);
  unsigned short* z2  = (unsigned short*)carve((size_t)Bb * T * HD * 2); // [B,T,H*D]
  unsigned short* qc  = (unsigned short*)carve((size_t)CH * T * D * 2);  // [CH,T,D]
  unsigned short* kc  = (unsigned short*)carve((size_t)CH * T * D * 2);
  unsigned short* vc  = (unsigned short*)carve((size_t)CH * T * D * 2);
  unsigned short* vTc = (unsigned short*)carve((size_t)CH * D * T * 2);  // [CH,D,T]
  unsigned short* Sc  = (unsigned short*)carve((size_t)CH * T * T * 2);  // [CH,T,T]
  unsigned short* woT = wqT;  // reuse: wqT dead after all QKV chunks... but
  // chunks interleave projections; wqT needed through last chunk, and woT
  // transpose runs after the loop -> safe.

  const dim3 tb32(32, 8);

  // --- prep ---
  convert_f32_bf16_kernel<<<(Bb * T * E / 4 + 255) / 256, 256, 0, stream>>>(
      x, xb, Bb * T * E / 4);
  transpose_conv_kernel<<<dim3(24, 24, 8), tb32, 0, stream>>>(wq, wqT, E, D);
  transpose_conv_kernel<<<dim3(24, 24, 8), tb32, 0, stream>>>(wk, wkT, E, D);
  transpose_conv_kernel<<<dim3(24, 24, 8), tb32, 0, stream>>>(wv, wvT, E, D);
  bosum_kernel<<<3, 256, 0, stream>>>(bo, bos);

  // --- chunked attention: CH heads per pass, all within one batch b ---
  const int nchunks = (Bb * H) / CH;
  for (int c = 0; c < nchunks; ++c) {
    const int z0 = c * CH;
    const int b  = z0 >> 3;     // CH divides 8, so chunk stays in one batch
    const int h0 = z0 & 7;
    const unsigned short* xbb = xb + (size_t)b * T * E;

    // Q/K/V projections: [1024,768] x [768,768]^T per head -> [CH,T,D]
    gemm_bt_kernel<false><<<dim3(6, 8, CH), 256, 0, stream>>>(
        xbb, wqT + (size_t)h0 * DE, qc, bq + (size_t)h0 * D, E,
        0LL, DE, TD, 0LL, 0, 0LL, 30, D, (long long)D, 1.0f);
    gemm_bt_kernel<false><<<dim3(6, 8, CH), 256, 0, stream>>>(
        xbb, wkT + (size_t)h0 * DE, kc, bk + (size_t)h0 * D, E,
        0LL, DE, TD, 0LL, 0, 0LL, 30, D, (long long)D, 1.0f);
    gemm_bt_kernel<false><<<dim3(6, 8, CH), 256, 0, stream>>>(
        xbb, wvT + (size_t)h0 * DE, vc, bv + (size_t)h0 * D, E,
        0LL, DE, TD, 0LL, 0, 0LL, 30, D, (long long)D, 1.0f);

    // v -> vT [CH,D,T]
    transpose_bf16_kernel<<<dim3(24, 32, CH), tb32, 0, stream>>>(vc, vTc, T, D);

    // S = scale * q k^T  [CH,T,T]
    gemm_bt_kernel<false><<<dim3(8, 8, CH), 256, 0, stream>>>(
        qc, kc, Sc, nullptr, D,
        TD, TD, TT, 0LL, 0, 0LL, 30, T, 0LL, 0.03608439182435161f);

    // softmax rows in-place
    softmax_kernel<<<CH * T, 256, 0, stream>>>(Sc);

    // z2[b, t, (h0+z)*D + n] = P * v
    gemm_bt_kernel<false><<<dim3(6, 8, CH), 256, 0, stream>>>(
        Sc, vTc, z2 + (size_t)b * T * HD + (size_t)h0 * D, nullptr, T,
        TT, DT, (long long)D, 0LL, 0, 0LL, 30, HD, 0LL, 1.0f);
  }

  // --- out = z2 * woT^T + bos : [4096,6144] x [6144,768]^T -> fp32 ---
  transpose_conv_kernel<<<dim3(24, 192, 1), tb32, 0, stream>>>(wo, woT, HD, E);
  gemm_bt_kernel<true><<<dim3(6, 32, 1), 256, 0, stream>>>(
      z2, woT, out, bos, HD,
      0LL, 0LL, 0LL, 0LL, 0, 0LL, 30, E, 0LL, 1.0f);
}

// Round 3
// 481.940 us; speedup vs baseline: 1.7113x; 1.7113x over previous
//
#include <hip/hip_runtime.h>
#include <hip/hip_bf16.h>

// ---------------------------------------------------------------------------
// MultiHeadAttention: B=4, T=1024, E=768, D=768, H=8, per-head full-width proj
// All GEMMs via bf16 MFMA (m97 128x128 structure) + XCD swizzle.
// Tier ALL32 (ws >= ~246MB): fused QKV (z=24), S/PV over all 32 (b,h),
// split-K=4 out-proj, aliased workspace. Else: proven R2 chunked fallback.
// ---------------------------------------------------------------------------

typedef __bf16 bf16x8 __attribute__((ext_vector_type(8)));
typedef float  f32x4  __attribute__((ext_vector_type(4)));
typedef short  s16x4  __attribute__((ext_vector_type(4)));

#define AS1 __attribute__((address_space(1)))
#define AS3 __attribute__((address_space(3)))

__device__ inline void gload_lds16(const void* g, void* l) {
  __builtin_amdgcn_global_load_lds((AS1 const void*)g, (AS3 void*)l, 16, 0, 0);
}

__device__ inline unsigned short f2bf(float f) {  // RNE f32 -> bf16 bits
  union { float f; unsigned u; } c; c.f = f;
  unsigned r = c.u + 0x7FFF + ((c.u >> 16) & 1);
  return (unsigned short)(r >> 16);
}
__device__ inline float bf2f(unsigned short u) {
  return __uint_as_float(((unsigned)u) << 16);
}

// XCD-aware bijective remap (T1); valid when total blocks % 8 == 0
__device__ inline void swizzle_bid(int& bx, int& by, int& bz) {
  const int gx = gridDim.x, gy = gridDim.y, gz = gridDim.z;
  const int n = gx * gy * gz;
  if ((n & 7) == 0) {
    int lin = (blockIdx.z * gy + blockIdx.y) * gx + blockIdx.x;
    lin = (lin & 7) * (n >> 3) + (lin >> 3);
    bz = lin / (gx * gy);
    const int rem = lin - bz * gx * gy;
    by = rem / gx;
    bx = rem - by * gx;
  } else {
    bx = blockIdx.x; by = blockIdx.y; bz = blockIdx.z;
  }
}

// ---------------------------------------------------------------------------
// GEMM: C = scale * A * Bt^T (+ bias[z*biasZ + n]); A:[M,lda] bf16, Bt:[N,ldb]
//   zoff  = (z>>zShift)*cZhi + (z & ((1<<zShift)-1))*cZlo
//   rowoff= (m>>rowShift)*cRowHi + (m & ((1<<rowShift)-1))*ldc
//   C[zoff + rowoff + n]
// Grid: (N/128, M/128, Z). 256 threads = 4 waves, each wave 64x64 output.
// ---------------------------------------------------------------------------
template<bool OUT_F32>
__global__ __launch_bounds__(256, 2)
void gemm_bt_kernel(const unsigned short* __restrict__ A,
                    const unsigned short* __restrict__ Bt,
                    void* __restrict__ Cout,
                    const float* __restrict__ bias,
                    int K, int lda, int ldb,
                    long long aZ, long long bZ,
                    long long cZhi, long long cZlo, int zShift,
                    long long cRowHi, int rowShift, int ldc,
                    long long biasZ, float scale)
{
  __shared__ unsigned short As[128 * 64];
  __shared__ unsigned short Bs[128 * 64];

  int ntile, mtile, z;
  swizzle_bid(ntile, mtile, z);

  const int tid  = threadIdx.x;
  const int wave = tid >> 6;
  const int lane = tid & 63;
  const int wm = wave >> 1, wn = wave & 1;

  const unsigned short* Ab = A  + (size_t)z * aZ + (size_t)mtile * 128 * lda;
  const unsigned short* Bb = Bt + (size_t)z * bZ + (size_t)ntile * 128 * ldb;

  const int rlane = lane >> 3;          // 0..7 row within 8-row group
  const int ck    = (lane & 7) * 8;     // bf16 column within 64-wide K tile

  f32x4 acc[4][4] = {};

  const int nkt = K >> 6;
  for (int kt = 0; kt < nkt; ++kt) {
    const int kbase = kt * 64;
    __syncthreads();
#pragma unroll
    for (int i = 0; i < 4; ++i) {
      const int r = wave * 32 + i * 8;          // wave-uniform base row
      gload_lds16(Ab + (size_t)(r + rlane) * lda + kbase + ck, &As[r * 64]);
      gload_lds16(Bb + (size_t)(r + rlane) * ldb + kbase + ck, &Bs[r * 64]);
    }
    __syncthreads();
#pragma unroll
    for (int kk = 0; kk < 2; ++kk) {
      const int koff = kk * 32 + (lane >> 4) * 8;
      bf16x8 af[4], bfr[4];
#pragma unroll
      for (int f = 0; f < 4; ++f) {
        af[f]  = *(const bf16x8*)&As[(wm * 64 + f * 16 + (lane & 15)) * 64 + koff];
        bfr[f] = *(const bf16x8*)&Bs[(wn * 64 + f * 16 + (lane & 15)) * 64 + koff];
      }
#pragma unroll
      for (int fm = 0; fm < 4; ++fm)
#pragma unroll
        for (int fn = 0; fn < 4; ++fn)
          acc[fm][fn] = __builtin_amdgcn_mfma_f32_16x16x32_bf16(af[fm], bfr[fn], acc[fm][fn], 0, 0, 0);
    }
  }

  // epilogue: C/D frag layout: col = lane&15, row = (lane>>4)*4 + j  [m89]
  const long long zoff = (long long)(z >> zShift) * cZhi
                       + (long long)(z & ((1 << zShift) - 1)) * cZlo;
#pragma unroll
  for (int fm = 0; fm < 4; ++fm) {
#pragma unroll
    for (int j = 0; j < 4; ++j) {
      const int m = mtile * 128 + wm * 64 + fm * 16 + (lane >> 4) * 4 + j;
      const long long rowoff = (long long)(m >> rowShift) * cRowHi
                             + (long long)(m & ((1 << rowShift) - 1)) * ldc;
#pragma unroll
      for (int fn = 0; fn < 4; ++fn) {
        const int n = ntile * 128 + wn * 64 + fn * 16 + (lane & 15);
        float v = acc[fm][fn][j] * scale;
        if (bias) v += bias[(size_t)z * biasZ + n];
        const long long cidx = zoff + rowoff + n;
        if (OUT_F32) ((float*)Cout)[cidx] = v;
        else ((unsigned short*)Cout)[cidx] = f2bf(v);
      }
    }
  }
}

// fp32 [Z][R][C] -> bf16 [Z][C][R] tile transpose+convert
__global__ void transpose_conv_kernel(const float* __restrict__ in,
                                      unsigned short* __restrict__ out,
                                      int R, int C)
{
  __shared__ float tile[32][33];
  const size_t zo = (size_t)blockIdx.z * R * C;
  const int c0 = blockIdx.x * 32, r0 = blockIdx.y * 32;
  const int tx = threadIdx.x, ty = threadIdx.y;
#pragma unroll
  for (int i = ty; i < 32; i += 8)
    tile[i][tx] = in[zo + (size_t)(r0 + i) * C + c0 + tx];
  __syncthreads();
#pragma unroll
  for (int i = ty; i < 32; i += 8)
    out[zo + (size_t)(c0 + i) * R + r0 + tx] = f2bf(tile[tx][i]);
}

// bf16 [Z][R][C] -> bf16 [Z][C][R]
__global__ void transpose_bf16_kernel(const unsigned short* __restrict__ in,
                                      unsigned short* __restrict__ out,
                                      int R, int C)
{
  __shared__ unsigned short tile[32][33];
  const size_t zo = (size_t)blockIdx.z * R * C;
  const int c0 = blockIdx.x * 32, r0 = blockIdx.y * 32;
  const int tx = threadIdx.x, ty = threadIdx.y;
#pragma unroll
  for (int i = ty; i < 32; i += 8)
    tile[i][tx] = in[zo + (size_t)(r0 + i) * C + c0 + tx];
  __syncthreads();
#pragma unroll
  for (int i = ty; i < 32; i += 8)
    out[zo + (size_t)(c0 + i) * R + r0 + tx] = tile[tx][i];
}

__global__ void convert_f32_bf16_kernel(const float* __restrict__ in,
                                        unsigned short* __restrict__ out, int n4)
{
  const int i = blockIdx.x * blockDim.x + threadIdx.x;
  if (i < n4) {
    const float4 f = ((const float4*)in)[i];
    s16x4 o;
    o[0] = (short)f2bf(f.x); o[1] = (short)f2bf(f.y);
    o[2] = (short)f2bf(f.z); o[3] = (short)f2bf(f.w);
    ((s16x4*)out)[i] = o;
  }
}

__global__ void bosum_kernel(const float* __restrict__ bo, float* __restrict__ bos)
{
  const int e = blockIdx.x * blockDim.x + threadIdx.x;
  if (e < 768) {
    float s = 0.f;
#pragma unroll
    for (int h = 0; h < 8; ++h) s += bo[h * 768 + e];
    bos[e] = s;
  }
}

// concat bq,bk,bv -> bqkv[24][768] (z = proj*8 + h)
__global__ void bconcat_kernel(const float* __restrict__ bq,
                               const float* __restrict__ bk,
                               const float* __restrict__ bv,
                               float* __restrict__ bqkv)
{
  const int i = blockIdx.x * blockDim.x + threadIdx.x;
  if (i < 24 * 768) {
    const int z = i / 768, d = i - z * 768;
    const float* src = (z < 8) ? bq : (z < 16) ? bk : bv;
    bqkv[i] = src[(z & 7) * 768 + d];
  }
}

// out[i] = sum_{kz<4} partials[kz][i] + bos[i%768], float4-vectorized
__global__ void reduce4_kernel(const float* __restrict__ partials,
                               const float* __restrict__ bos,
                               float* __restrict__ out, int n4)
{
  const int i = blockIdx.x * blockDim.x + threadIdx.x;
  if (i < n4) {
    const long long stride4 = 4096LL * 768 / 4;
    float4 a = ((const float4*)partials)[i];
    float4 b = ((const float4*)partials)[i + stride4];
    float4 c = ((const float4*)partials)[i + 2 * stride4];
    float4 d = ((const float4*)partials)[i + 3 * stride4];
    const int col = (i * 4) % 768;
    const float4 bo4 = *(const float4*)&bos[col];
    float4 r;
    r.x = a.x + b.x + c.x + d.x + bo4.x;
    r.y = a.y + b.y + c.y + d.y + bo4.y;
    r.z = a.z + b.z + c.z + d.z + bo4.z;
    r.w = a.w + b.w + c.w + d.w + bo4.w;
    ((float4*)out)[i] = r;
  }
}

// in-place row softmax on bf16 [rows][1024]; one block (256 thr) per row
__global__ __launch_bounds__(256)
void softmax_kernel(unsigned short* __restrict__ S)
{
  const size_t row = blockIdx.x;
  unsigned short* p = S + row * 1024;
  const int t = threadIdx.x;

  s16x4 raw = *((const s16x4*)p + t);
  float v[4];
#pragma unroll
  for (int j = 0; j < 4; ++j) v[j] = bf2f((unsigned short)raw[j]);

  float mx = fmaxf(fmaxf(v[0], v[1]), fmaxf(v[2], v[3]));
#pragma unroll
  for (int o = 1; o < 64; o <<= 1) mx = fmaxf(mx, __shfl_xor(mx, o));

  __shared__ float red[8];
  if ((t & 63) == 0) red[t >> 6] = mx;
  __syncthreads();
  mx = fmaxf(fmaxf(red[0], red[1]), fmaxf(red[2], red[3]));

  float e[4], s = 0.f;
#pragma unroll
  for (int j = 0; j < 4; ++j) { e[j] = __expf(v[j] - mx); s += e[j]; }
#pragma unroll
  for (int o = 1; o < 64; o <<= 1) s += __shfl_xor(s, o);
  if ((t & 63) == 0) red[4 + (t >> 6)] = s;
  __syncthreads();
  s = red[4] + red[5] + red[6] + red[7];
  const float inv = 1.0f / s;

  s16x4 outv;
#pragma unroll
  for (int j = 0; j < 4; ++j) outv[j] = (short)f2bf(e[j] * inv);
  *((s16x4*)p + t) = outv;
}

// ---------------------------------------------------------------------------
extern "C" void kernel_launch(void* const* d_in, const int* in_sizes, int n_in,
                              void* d_out, int out_size, void* d_ws, size_t ws_size,
                              hipStream_t stream)
{
  (void)in_sizes; (void)n_in; (void)out_size;
  constexpr int Bb = 4, T = 1024, E = 768, D = 768, H = 8;
  constexpr int HD = H * D;                           // 6144
  constexpr long long TD = (long long)T * D;          // 786432
  constexpr long long TT = (long long)T * T;          // 1048576
  constexpr long long DE = (long long)D * E;          // 589824
  constexpr long long DT = (long long)D * T;          // 786432
  constexpr long long BHTD = (long long)Bb * H * T * D;  // 25165824
  constexpr long long HTD = (long long)H * TD;        // 6291456
  constexpr float SCALE = 0.03608439182435161f;       // 1/sqrt(E)

  const float* x  = (const float*)d_in[0];
  const float* wq = (const float*)d_in[1];
  const float* bq = (const float*)d_in[2];
  const float* wk = (const float*)d_in[3];
  const float* bk = (const float*)d_in[4];
  const float* wv = (const float*)d_in[5];
  const float* bv = (const float*)d_in[6];
  const float* wo = (const float*)d_in[7];
  const float* bo = (const float*)d_in[8];
  float* out = (float*)d_out;

  unsigned char* wsb = (unsigned char*)d_ws;
  const dim3 tb32(32, 8);

  // ---- ALL32 tier peak footprint: 245,443,584 B ----
  if (ws_size >= 245443584ULL + 4096ULL) {
    // layout (byte offsets)
    unsigned short* woT   = (unsigned short*)(wsb + 0);            //  9,437,184
    float*          bos   = (float*)(wsb + 9437184);               //      3,072
    float*          bqkv  = (float*)(wsb + 9440256);               //     73,728
    unsigned short* vT    = (unsigned short*)(wsb + 9513984);      // 50,331,648
    unsigned short* qkv   = (unsigned short*)(wsb + 59845632);     // 3x 50,331,648
    unsigned short* q     = qkv;                                   // z2 aliases q
    unsigned short* k     = qkv + BHTD;
    unsigned short* v     = qkv + 2 * BHTD;
    unsigned short* xb    = (unsigned short*)(wsb + 210840576);    //  6,291,456
    unsigned short* wqkvT = (unsigned short*)(wsb + 217132032);    // 28,311,552
    unsigned short* S     = v;          // overlays dead v+xb+wqkvT (67,108,864)
    float*          part  = (float*)k;  // overlays dead k (4x12.6MB = 50,331,648)
    unsigned short* z2    = q;          // overlays dead q

    // --- prep ---
    convert_f32_bf16_kernel<<<3072, 256, 0, stream>>>(x, xb, Bb * T * E / 4);
    transpose_conv_kernel<<<dim3(24, 24, 8), tb32, 0, stream>>>(wq, wqkvT, E, D);
    transpose_conv_kernel<<<dim3(24, 24, 8), tb32, 0, stream>>>(wk, wqkvT + 8 * DE, E, D);
    transpose_conv_kernel<<<dim3(24, 24, 8), tb32, 0, stream>>>(wv, wqkvT + 16 * DE, E, D);
    transpose_conv_kernel<<<dim3(24, 192, 1), tb32, 0, stream>>>(wo, woT, HD, E);
    bosum_kernel<<<3, 256, 0, stream>>>(bo, bos);
    bconcat_kernel<<<72, 256, 0, stream>>>(bq, bk, bv, bqkv);

    // --- fused QKV: z = proj*8 + h; C[proj*BHTD + b*HTD + h*TD + t*D + n] ---
    gemm_bt_kernel<false><<<dim3(6, 32, 24), 256, 0, stream>>>(
        xb, wqkvT, qkv, bqkv, E, E, E,
        0LL, DE, BHTD, TD, 3, HTD, 10, D, 768LL, 1.0f);

    // --- v -> vT [B,H,D,T] ---
    transpose_bf16_kernel<<<dim3(24, 32, 32), tb32, 0, stream>>>(v, vT, T, D);

    // --- S = scale * q k^T  [BH,T,T] over all 32 (b,h) ---
    gemm_bt_kernel<false><<<dim3(8, 8, 32), 256, 0, stream>>>(
        q, k, S, nullptr, D, D, D,
        TD, TD, TT, 0LL, 0, 0LL, 30, T, 0LL, SCALE);

    // --- softmax all rows ---
    softmax_kernel<<<Bb * H * T, 256, 0, stream>>>(S);

    // --- z2[b,t,h*D+n] = P v : z = b*8+h ---
    gemm_bt_kernel<false><<<dim3(6, 8, 32), 256, 0, stream>>>(
        S, vT, z2, nullptr, T, T, T,
        TT, DT, (long long)T * HD, (long long)D, 3, 0LL, 30, HD, 0LL, 1.0f);

    // --- out-proj split-K=4: partials[kz][4096][768] fp32 ---
    gemm_bt_kernel<true><<<dim3(6, 32, 4), 256, 0, stream>>>(
        z2, woT, part, nullptr, 1536, HD, HD,
        1536LL, 1536LL, 3145728LL, 0LL, 0, 0LL, 30, E, 0LL, 1.0f);
    reduce4_kernel<<<3072, 256, 0, stream>>>(part, bos, out, 4096 * 768 / 4);
    return;
  }

  // ---------------- fallback: proven R2 chunked path ----------------
  const size_t FIXED = 84937728ULL;
  const size_t PERCH = 8388608ULL;
  int CH = 8;
  while (CH > 1 && FIXED + (size_t)CH * PERCH > ws_size) CH >>= 1;

  size_t off = 0;
  auto carve = [&](size_t bytes) -> void* {
    void* p = wsb + off;
    off += (bytes + 255) & ~(size_t)255;
    return p;
  };
  unsigned short* xb  = (unsigned short*)carve((size_t)Bb * T * E * 2);
  unsigned short* wqT = (unsigned short*)carve((size_t)H * D * E * 2);
  unsigned short* wkT = (unsigned short*)carve((size_t)H * D * E * 2);
  unsigned short* wvT = (unsigned short*)carve((size_t)H * D * E * 2);
  float*          bos = (float*)carve(E * 4);
  unsigned short* z2  = (unsigned short*)carve((size_t)Bb * T * HD * 2);
  unsigned short* qc  = (unsigned short*)carve((size_t)CH * T * D * 2);
  unsigned short* kc  = (unsigned short*)carve((size_t)CH * T * D * 2);
  unsigned short* vc  = (unsigned short*)carve((size_t)CH * T * D * 2);
  unsigned short* vTc = (unsigned short*)carve((size_t)CH * D * T * 2);
  unsigned short* Sc  = (unsigned short*)carve((size_t)CH * T * T * 2);
  unsigned short* woT = wqT;  // wqT dead after chunk loop

  convert_f32_bf16_kernel<<<3072, 256, 0, stream>>>(x, xb, Bb * T * E / 4);
  transpose_conv_kernel<<<dim3(24, 24, 8), tb32, 0, stream>>>(wq, wqT, E, D);
  transpose_conv_kernel<<<dim3(24, 24, 8), tb32, 0, stream>>>(wk, wkT, E, D);
  transpose_conv_kernel<<<dim3(24, 24, 8), tb32, 0, stream>>>(wv, wvT, E, D);
  bosum_kernel<<<3, 256, 0, stream>>>(bo, bos);

  const int nchunks = (Bb * H) / CH;
  for (int c = 0; c < nchunks; ++c) {
    const int z0 = c * CH;
    const int b  = z0 >> 3;
    const int h0 = z0 & 7;
    const unsigned short* xbb = xb + (size_t)b * T * E;

    gemm_bt_kernel<false><<<dim3(6, 8, CH), 256, 0, stream>>>(
        xbb, wqT + (size_t)h0 * DE, qc, bq + (size_t)h0 * D, E, E, E,
        0LL, DE, TD, 0LL, 0, 0LL, 30, D, (long long)D, 1.0f);
    gemm_bt_kernel<false><<<dim3(6, 8, CH), 256, 0, stream>>>(
        xbb, wkT + (size_t)h0 * DE, kc, bk + (size_t)h0 * D, E, E, E,
        0LL, DE, TD, 0LL, 0, 0LL, 30, D, (long long)D, 1.0f);
    gemm_bt_kernel<false><<<dim3(6, 8, CH), 256, 0, stream>>>(
        xbb, wvT + (size_t)h0 * DE, vc, bv + (size_t)h0 * D, E, E, E,
        0LL, DE, TD, 0LL, 0, 0LL, 30, D, (long long)D, 1.0f);

    transpose_bf16_kernel<<<dim3(24, 32, CH), tb32, 0, stream>>>(vc, vTc, T, D);

    gemm_bt_kernel<false><<<dim3(8, 8, CH), 256, 0, stream>>>(
        qc, kc, Sc, nullptr, D, D, D,
        TD, TD, TT, 0LL, 0, 0LL, 30, T, 0LL, SCALE);

    softmax_kernel<<<CH * T, 256, 0, stream>>>(Sc);

    gemm_bt_kernel<false><<<dim3(6, 8, CH), 256, 0, stream>>>(
        Sc, vTc, z2 + (size_t)b * T * HD + (size_t)h0 * D, nullptr, T, T, T,
        TT, DT, (long long)D, 0LL, 0, 0LL, 30, HD, 0LL, 1.0f);
  }

  transpose_conv_kernel<<<dim3(24, 192, 1), tb32, 0, stream>>>(wo, woT, HD, E);
  gemm_bt_kernel<true><<<dim3(6, 32, 1), 256, 0, stream>>>(
      z2, woT, out, bos, HD, HD, HD,
      0LL, 0LL, 0LL, 0LL, 0, 0LL, 30, E, 0LL, 1.0f);
}